// Round 2
// baseline (431.543 us; speedup 1.0000x reference)
//
#include <hip/hip_runtime.h>
#include <hip/hip_bf16.h>
#include <stdint.h>

typedef __bf16 bf16;
typedef __attribute__((ext_vector_type(8))) __bf16 bf16x8;
typedef __attribute__((ext_vector_type(4))) float f32x4;

#define NH 16
#define DH 64
#define POOL 8
#define BATCH 4
#define SEQ 4096
#define DIMV 1024
#define QKV_N (3*DIMV)
#define M_TOTAL (BATCH*SEQ)
#define SCALE_F 0.125f

#define AS1(p) ((const __attribute__((address_space(1))) void*)(p))
#define AS3(p) ((__attribute__((address_space(3))) void*)(p))

// ---------------- elementwise fp32 -> bf16 (8 elems/thread) ----------------
__global__ void convert_x(const float* __restrict__ in, bf16* __restrict__ out) {
  size_t i = ((size_t)blockIdx.x * 256 + threadIdx.x) * 8;
  float4 f0 = *(const float4*)(in + i);
  float4 f1 = *(const float4*)(in + i + 4);
  bf16x8 o;
  o[0] = (bf16)f0.x; o[1] = (bf16)f0.y; o[2] = (bf16)f0.z; o[3] = (bf16)f0.w;
  o[4] = (bf16)f1.x; o[5] = (bf16)f1.y; o[6] = (bf16)f1.z; o[7] = (bf16)f1.w;
  *(bf16x8*)(out + i) = o;
}

// ---------------- transpose fp32 [R][C] -> bf16 [C][R] ----------------
__global__ void transpose_f32_bf16(const float* __restrict__ in, bf16* __restrict__ out,
                                   int R, int C) {
  __shared__ float tile[32][33];
  int c0 = blockIdx.x * 32, r0 = blockIdx.y * 32;
  int tx = threadIdx.x & 31, ty = threadIdx.x >> 5;   // 256 threads: ty 0..7
  for (int i = ty; i < 32; i += 8)
    tile[i][tx] = in[(size_t)(r0 + i) * C + c0 + tx];
  __syncthreads();
  for (int i = ty; i < 32; i += 8)
    out[(size_t)(c0 + i) * R + r0 + tx] = (bf16)tile[tx][i];
}

// ---------------- MFMA GEMM: C[M][N] = A[M][K] * B^T (B stored [N][K]) ----------------
// 128x128 tile, BK=32, 256 threads = 4 waves (2x2), each wave 64x64 (4x4 of 16x16x32)
template <typename CT, bool WITH_BIAS>
__global__ __launch_bounds__(256)
void gemm_bt(const bf16* __restrict__ A, const bf16* __restrict__ B,
             CT* __restrict__ C, const float* __restrict__ bias,
             int M, int N, int K) {
  __shared__ bf16 As[128 * 32];
  __shared__ bf16 Bs[128 * 32];
  const int tid  = threadIdx.x;
  const int w    = tid >> 6;
  const int lane = tid & 63;
  const int m0 = blockIdx.y * 128, n0 = blockIdx.x * 128;
  const int wm = (w & 1) * 64, wn = (w >> 1) * 64;

  f32x4 acc[4][4] = {};

  // staging: each wave stages 2 groups of 16 rows for A and B.
  const int g0 = w * 2;
  const bf16* Ap0 = A + (size_t)(m0 + g0 * 16 + (lane >> 2)) * K + (lane & 3) * 8;
  const bf16* Ap1 = Ap0 + (size_t)16 * K;
  const bf16* Bp0 = B + (size_t)(n0 + g0 * 16 + (lane >> 2)) * K + (lane & 3) * 8;
  const bf16* Bp1 = Bp0 + (size_t)16 * K;
  bf16* AsW0 = As + g0 * 512;        // 512 elems = 1024 B per group
  bf16* AsW1 = As + (g0 + 1) * 512;
  bf16* BsW0 = Bs + g0 * 512;
  bf16* BsW1 = Bs + (g0 + 1) * 512;

  for (int k0 = 0; k0 < K; k0 += 32) {
    __syncthreads();
    __builtin_amdgcn_global_load_lds(AS1(Ap0 + k0), AS3(AsW0), 16, 0, 0);
    __builtin_amdgcn_global_load_lds(AS1(Ap1 + k0), AS3(AsW1), 16, 0, 0);
    __builtin_amdgcn_global_load_lds(AS1(Bp0 + k0), AS3(BsW0), 16, 0, 0);
    __builtin_amdgcn_global_load_lds(AS1(Bp1 + k0), AS3(BsW1), 16, 0, 0);
    __syncthreads();

    bf16x8 a[4], b[4];
#pragma unroll
    for (int i = 0; i < 4; ++i)
      a[i] = *(const bf16x8*)&As[(wm + i * 16 + (lane & 15)) * 32 + (lane >> 4) * 8];
#pragma unroll
    for (int j = 0; j < 4; ++j)
      b[j] = *(const bf16x8*)&Bs[(wn + j * 16 + (lane & 15)) * 32 + (lane >> 4) * 8];
#pragma unroll
    for (int i = 0; i < 4; ++i)
#pragma unroll
      for (int j = 0; j < 4; ++j)
        acc[i][j] = __builtin_amdgcn_mfma_f32_16x16x32_bf16(a[i], b[j], acc[i][j], 0, 0, 0);
  }

  // epilogue: C/D layout col=lane&15, row=(lane>>4)*4+r
  const int cr = (lane >> 4) * 4;
  const int cc = lane & 15;
#pragma unroll
  for (int i = 0; i < 4; ++i) {
#pragma unroll
    for (int j = 0; j < 4; ++j) {
      int row = m0 + wm + i * 16 + cr;
      int col = n0 + wn + j * 16 + cc;
      float bb = WITH_BIAS ? bias[col] : 0.0f;
#pragma unroll
      for (int r = 0; r < 4; ++r)
        C[(size_t)(row + r) * N + col] = (CT)(acc[i][j][r] + bb);
    }
  }
}

// ---------------- agent pooling: agent[b,h,p,d] = mean over 512 t of q ----------------
__global__ void agent_pool(const bf16* __restrict__ qkv, float* __restrict__ agent) {
  int bid = blockIdx.x;                 // 512 = b*h*p
  int p = bid & 7, h = (bid >> 3) & 15, b = bid >> 7;
  int d = threadIdx.x & 63, c = threadIdx.x >> 6;   // c 0..3
  const bf16* base = qkv + (size_t)(b * SEQ + p * 512) * QKV_N + h * DH + d;
  float s = 0.f;
  for (int i = c * 128; i < c * 128 + 128; ++i)
    s += (float)base[(size_t)i * QKV_N];
  __shared__ float red[4][64];
  red[c][d] = s;
  __syncthreads();
  if (c == 0) {
    float v = (red[0][d] + red[1][d] + red[2][d] + red[3][d]) * (1.0f / 512.0f);
    agent[((b * NH + h) * POOL + p) * DH + d] = v;
  }
}

// ---------------- stage 1 scores: s1[b,h,p,t] = SCALE * dot(agent, k) ----------------
__global__ void stage1_scores(const bf16* __restrict__ qkv, const float* __restrict__ agent,
                              float* __restrict__ s1) {
  int b = blockIdx.z, h = blockIdx.y;
  int t = blockIdx.x * 256 + threadIdx.x;
  __shared__ float ag[8][64];
  for (int i = threadIdx.x; i < 512; i += 256)
    ag[i >> 6][i & 63] = agent[(size_t)((b * NH + h) * POOL) * DH + i] * SCALE_F;
  __syncthreads();
  const bf16* krow = qkv + (size_t)(b * SEQ + t) * QKV_N + DIMV + h * DH;
  float sc[8] = {};
#pragma unroll
  for (int dc = 0; dc < 8; ++dc) {
    bf16x8 k8 = *(const bf16x8*)(krow + dc * 8);
#pragma unroll
    for (int e = 0; e < 8; ++e) {
      float kv = (float)k8[e];
#pragma unroll
      for (int p = 0; p < 8; ++p) sc[p] += ag[p][dc * 8 + e] * kv;
    }
  }
  size_t base = (size_t)((b * NH + h) * POOL) * SEQ + t;
#pragma unroll
  for (int p = 0; p < 8; ++p) s1[base + (size_t)p * SEQ] = sc[p];
}

// ---------------- softmax over T=4096 per row, in place ----------------
__global__ void softmax_rows(float* __restrict__ s) {
  const int T = 4096;
  float* row = s + (size_t)blockIdx.x * T;
  int tid = threadIdx.x;
  float v[16];
  float m = -1e30f;
#pragma unroll
  for (int j = 0; j < 16; ++j) { v[j] = row[tid + j * 256]; m = fmaxf(m, v[j]); }
#pragma unroll
  for (int o = 32; o; o >>= 1) m = fmaxf(m, __shfl_xor(m, o));
  __shared__ float redm[4];
  if ((tid & 63) == 0) redm[tid >> 6] = m;
  __syncthreads();
  m = fmaxf(fmaxf(redm[0], redm[1]), fmaxf(redm[2], redm[3]));
  float sum = 0.f;
#pragma unroll
  for (int j = 0; j < 16; ++j) { v[j] = expf(v[j] - m); sum += v[j]; }
#pragma unroll
  for (int o = 32; o; o >>= 1) sum += __shfl_xor(sum, o);
  __shared__ float reds[4];
  if ((tid & 63) == 0) reds[tid >> 6] = sum;
  __syncthreads();
  sum = reds[0] + reds[1] + reds[2] + reds[3];
  float inv = 1.0f / sum;
#pragma unroll
  for (int j = 0; j < 16; ++j) row[tid + j * 256] = v[j] * inv;
}

// ---------------- v_agent[b,h,p,d] = sum_t p1[t] * v[t,d] (atomic partials) ----------------
__global__ void v_agent_k(const bf16* __restrict__ qkv, const float* __restrict__ p1,
                          float* __restrict__ vag) {
  int b = blockIdx.z, h = blockIdx.y, tq = blockIdx.x;  // tq 0..7
  int d = threadIdx.x & 63, c = threadIdx.x >> 6;        // c 0..3
  int t0 = tq * 512 + c * 128;
  const bf16* vbase = qkv + (size_t)(b * SEQ + t0) * QKV_N + 2 * DIMV + h * DH + d;
  const float* pbase = p1 + (size_t)((b * NH + h) * POOL) * SEQ + t0;
  float acc[8] = {};
  for (int i = 0; i < 128; ++i) {
    float vv = (float)vbase[(size_t)i * QKV_N];
#pragma unroll
    for (int p = 0; p < 8; ++p) acc[p] += pbase[(size_t)p * SEQ + i] * vv;
  }
  __shared__ float red[4][8][64];
#pragma unroll
  for (int p = 0; p < 8; ++p) red[c][p][d] = acc[p];
  __syncthreads();
#pragma unroll
  for (int pp = c; pp < 8; pp += 4) {
    float sv = red[0][pp][d] + red[1][pp][d] + red[2][pp][d] + red[3][pp][d];
    atomicAdd(&vag[((b * NH + h) * POOL + pp) * DH + d], sv);
  }
}

// ---------------- stage 2: per (b,h,t): softmax(q*SCALE . agent) @ v_agent ----------------
__global__ void stage2_out(const bf16* __restrict__ qkv, const float* __restrict__ agent,
                           const float* __restrict__ vag, bf16* __restrict__ outa) {
  int b = blockIdx.z, h = blockIdx.y;
  int t = blockIdx.x * 256 + threadIdx.x;
  __shared__ float ag[8][64], va[8][64];
  for (int i = threadIdx.x; i < 512; i += 256) {
    ag[i >> 6][i & 63] = agent[(size_t)((b * NH + h) * POOL) * DH + i] * SCALE_F;
    va[i >> 6][i & 63] = vag[(size_t)((b * NH + h) * POOL) * DH + i];
  }
  __syncthreads();
  const bf16* qrow = qkv + (size_t)(b * SEQ + t) * QKV_N + h * DH;
  float sc[8] = {};
#pragma unroll
  for (int dc = 0; dc < 8; ++dc) {
    bf16x8 q8 = *(const bf16x8*)(qrow + dc * 8);
#pragma unroll
    for (int e = 0; e < 8; ++e) {
      float qv = (float)q8[e];
#pragma unroll
      for (int p = 0; p < 8; ++p) sc[p] += ag[p][dc * 8 + e] * qv;
    }
  }
  float m = sc[0];
#pragma unroll
  for (int p = 1; p < 8; ++p) m = fmaxf(m, sc[p]);
  float wsum = 0.f, wgt[8];
#pragma unroll
  for (int p = 0; p < 8; ++p) { wgt[p] = expf(sc[p] - m); wsum += wgt[p]; }
  float inv = 1.0f / wsum;
#pragma unroll
  for (int p = 0; p < 8; ++p) wgt[p] *= inv;
  bf16* orow = outa + (size_t)(b * SEQ + t) * DIMV + h * DH;
#pragma unroll
  for (int dc = 0; dc < 8; ++dc) {
    bf16x8 o8;
#pragma unroll
    for (int e = 0; e < 8; ++e) {
      float vv = 0.f;
#pragma unroll
      for (int p = 0; p < 8; ++p) vv += wgt[p] * va[p][dc * 8 + e];
      o8[e] = (bf16)vv;
    }
    *(bf16x8*)(orow + dc * 8) = o8;
  }
}

extern "C" void kernel_launch(void* const* d_in, const int* in_sizes, int n_in,
                              void* d_out, int out_size, void* d_ws, size_t ws_size,
                              hipStream_t stream) {
  const float* x    = (const float*)d_in[0];   // [4,4096,1024] fp32
  const float* Wqkv = (const float*)d_in[1];   // [1024,3072]   fp32
  const float* Wo   = (const float*)d_in[2];   // [1024,1024]   fp32
  const float* bo   = (const float*)d_in[3];   // [1024]        fp32
  float* out = (float*)d_out;                  // [4,4096,1024] fp32

  // workspace layout (bytes):
  //   [0,   6M)  WqkvT bf16 [3072][1024]
  //   [6M,  8M)  WoT   bf16 [1024][1024]
  //   [8M, 104M) qkv   bf16 [16384][3072]
  //   [104M, ..) union:
  //       xb  bf16 [16384][1024]          (33.5 MB, dead after gemm1)
  //       outa bf16 [16384][1024] (32MB) | agent (128K) | vag (128K) | p1 (8MB)
  char* ws = (char*)d_ws;
  bf16* WqkvT = (bf16*)ws;
  bf16* WoT   = (bf16*)(ws + (size_t)QKV_N * DIMV * 2);
  bf16* qkv   = (bf16*)(ws + (size_t)QKV_N * DIMV * 2 + (size_t)DIMV * DIMV * 2);
  char* ws3   = ws + (size_t)QKV_N * DIMV * 2 + (size_t)DIMV * DIMV * 2
                   + (size_t)M_TOTAL * QKV_N * 2;
  bf16*  xb    = (bf16*)ws3;
  bf16*  outa  = (bf16*)ws3;
  float* agent = (float*)(ws3 + (size_t)M_TOTAL * DIMV * 2);
  float* vag   = (float*)(ws3 + (size_t)M_TOTAL * DIMV * 2 + 512 * 64 * 4);
  float* p1    = (float*)(ws3 + (size_t)M_TOTAL * DIMV * 2 + 2 * 512 * 64 * 4);

  // x -> bf16
  convert_x<<<(size_t)M_TOTAL * DIMV / (256 * 8), 256, 0, stream>>>(x, xb);
  // weights -> bf16, transposed to [N][K]
  transpose_f32_bf16<<<dim3(QKV_N / 32, DIMV / 32), 256, 0, stream>>>(Wqkv, WqkvT, DIMV, QKV_N);
  transpose_f32_bf16<<<dim3(DIMV / 32, DIMV / 32), 256, 0, stream>>>(Wo, WoT, DIMV, DIMV);

  // qkv = x @ Wqkv   (bf16 out)
  gemm_bt<bf16, false><<<dim3(QKV_N / 128, M_TOTAL / 128), 256, 0, stream>>>(
      xb, WqkvT, qkv, nullptr, M_TOTAL, QKV_N, DIMV);

  // vag must be zeroed AFTER gemm1 (vag overlays xb region)
  hipMemsetAsync(vag, 0, (size_t)512 * 64 * 4, stream);

  agent_pool<<<512, 256, 0, stream>>>(qkv, agent);
  stage1_scores<<<dim3(SEQ / 256, NH, BATCH), 256, 0, stream>>>(qkv, agent, p1);
  softmax_rows<<<512, 256, 0, stream>>>(p1);
  v_agent_k<<<dim3(8, NH, BATCH), 256, 0, stream>>>(qkv, p1, vag);
  stage2_out<<<dim3(SEQ / 256, NH, BATCH), 256, 0, stream>>>(qkv, agent, vag, outa);

  // out = outa @ Wo + bo   (fp32 out)
  gemm_bt<float, true><<<dim3(DIMV / 128, M_TOTAL / 128), 256, 0, stream>>>(
      outa, WoT, out, bo, M_TOTAL, DIMV, DIMV);
}

// Round 3
// 421.151 us; speedup vs baseline: 1.0247x; 1.0247x over previous
//
#include <hip/hip_runtime.h>
#include <hip/hip_bf16.h>
#include <stdint.h>

typedef __bf16 bf16;
typedef __attribute__((ext_vector_type(8))) __bf16 bf16x8;
typedef __attribute__((ext_vector_type(2))) __bf16 bf16x2;
typedef __attribute__((ext_vector_type(4))) float f32x4;

#define NH 16
#define DH 64
#define POOL 8
#define BATCH 4
#define SEQ 4096
#define DIMV 1024
#define QKV_N (3*DIMV)
#define M_TOTAL (BATCH*SEQ)
#define SCALE_F 0.125f
#define BH (BATCH*NH)              // 64
#define QKVSZ ((size_t)BH*SEQ*DH)  // elems per q/k/v plane
#define TCH 8                      // t-split chunks for stage1
#define TCL (SEQ/TCH)              // 512 t per chunk

#define AS1(p) ((const __attribute__((address_space(1))) void*)(p))
#define AS3(p) ((__attribute__((address_space(3))) void*)(p))

// ---------------- elementwise fp32 -> bf16 (8 elems/thread) ----------------
__global__ void convert_x(const float* __restrict__ in, bf16* __restrict__ out) {
  size_t i = ((size_t)blockIdx.x * 256 + threadIdx.x) * 8;
  float4 f0 = *(const float4*)(in + i);
  float4 f1 = *(const float4*)(in + i + 4);
  bf16x8 o;
  o[0] = (bf16)f0.x; o[1] = (bf16)f0.y; o[2] = (bf16)f0.z; o[3] = (bf16)f0.w;
  o[4] = (bf16)f1.x; o[5] = (bf16)f1.y; o[6] = (bf16)f1.z; o[7] = (bf16)f1.w;
  *(bf16x8*)(out + i) = o;
}

// ---------------- transpose fp32 [R][C] -> bf16 [C][R] ----------------
__global__ void transpose_f32_bf16(const float* __restrict__ in, bf16* __restrict__ out,
                                   int R, int C) {
  __shared__ float tile[32][33];
  int c0 = blockIdx.x * 32, r0 = blockIdx.y * 32;
  int tx = threadIdx.x & 31, ty = threadIdx.x >> 5;
  for (int i = ty; i < 32; i += 8)
    tile[i][tx] = in[(size_t)(r0 + i) * C + c0 + tx];
  __syncthreads();
  for (int i = ty; i < 32; i += 8)
    out[(size_t)(c0 + i) * R + r0 + tx] = (bf16)tile[tx][i];
}

// ---------------- MFMA GEMM: C = A[M][K] * B^T (B stored [N][K]) ----------------
// MODE 0: output bf16, scattered into split q/k/v planes [which][bh][t][d]
// MODE 1: output fp32 row-major with fp32 bias
// LDS XOR swizzle: slot = kc ^ ((row>>1)&3) breaks the 8-way ds_read_b128 conflict.
template <int MODE>
__global__ __launch_bounds__(256)
void gemm_bt(const bf16* __restrict__ A, const bf16* __restrict__ B,
             void* __restrict__ Cv, const float* __restrict__ bias,
             int M, int N, int K) {
  __shared__ bf16 As[128 * 32];
  __shared__ bf16 Bs[128 * 32];
  const int tid  = threadIdx.x;
  const int w    = tid >> 6;
  const int lane = tid & 63;
  const int m0 = blockIdx.y * 128, n0 = blockIdx.x * 128;
  const int wm = (w & 1) * 64, wn = (w >> 1) * 64;

  f32x4 acc[4][4] = {};

  // staging: wave w stages rows [w*32, w*32+32) of both tiles (2 groups of 16).
  // lane -> (row-in-group = lane>>2, swizzled k-chunk)
  const int g0  = w * 2;
  const int rig = lane >> 2;
  const int kcs = (lane & 3) ^ ((rig >> 1) & 3);
  const bf16* Ap0 = A + (size_t)(m0 + g0 * 16 + rig) * K + kcs * 8;
  const bf16* Ap1 = Ap0 + (size_t)16 * K;
  const bf16* Bp0 = B + (size_t)(n0 + g0 * 16 + rig) * K + kcs * 8;
  const bf16* Bp1 = Bp0 + (size_t)16 * K;
  bf16* AsW0 = As + g0 * 512;
  bf16* AsW1 = As + (g0 + 1) * 512;
  bf16* BsW0 = Bs + g0 * 512;
  bf16* BsW1 = Bs + (g0 + 1) * 512;

  for (int k0 = 0; k0 < K; k0 += 32) {
    __syncthreads();
    __builtin_amdgcn_global_load_lds(AS1(Ap0 + k0), AS3(AsW0), 16, 0, 0);
    __builtin_amdgcn_global_load_lds(AS1(Ap1 + k0), AS3(AsW1), 16, 0, 0);
    __builtin_amdgcn_global_load_lds(AS1(Bp0 + k0), AS3(BsW0), 16, 0, 0);
    __builtin_amdgcn_global_load_lds(AS1(Bp1 + k0), AS3(BsW1), 16, 0, 0);
    __syncthreads();

    bf16x8 a[4], b[4];
    const int C = lane >> 4;
#pragma unroll
    for (int i = 0; i < 4; ++i) {
      int ar = wm + i * 16 + (lane & 15);
      int sw = C ^ ((ar >> 1) & 3);
      a[i] = *(const bf16x8*)&As[ar * 32 + sw * 8];
    }
#pragma unroll
    for (int j = 0; j < 4; ++j) {
      int br = wn + j * 16 + (lane & 15);
      int sw = C ^ ((br >> 1) & 3);
      b[j] = *(const bf16x8*)&Bs[br * 32 + sw * 8];
    }
#pragma unroll
    for (int i = 0; i < 4; ++i)
#pragma unroll
      for (int j = 0; j < 4; ++j)
        acc[i][j] = __builtin_amdgcn_mfma_f32_16x16x32_bf16(a[i], b[j], acc[i][j], 0, 0, 0);
  }

  // epilogue: C/D layout col=lane&15, row=(lane>>4)*4+r
  const int cr = (lane >> 4) * 4;
  const int cc = lane & 15;
#pragma unroll
  for (int i = 0; i < 4; ++i) {
#pragma unroll
    for (int j = 0; j < 4; ++j) {
      int rowb = m0 + wm + i * 16 + cr;
      if (MODE == 1) {
        float* Cp = (float*)Cv;
        int col = n0 + wn + j * 16 + cc;
        float bb = bias[col];
#pragma unroll
        for (int r = 0; r < 4; ++r)
          Cp[(size_t)(rowb + r) * N + col] = acc[i][j][r] + bb;
      } else {
        bf16* Cp = (bf16*)Cv;
        int nbase = n0 + wn + j * 16;          // 16-aligned, within one 64-wide head
        int which = nbase >> 10;
        int hh    = (nbase >> 6) & 15;
        int dd    = (nbase & 63) + cc;
        int bb_   = rowb >> 12;                // batch (uniform per block)
#pragma unroll
        for (int r = 0; r < 4; ++r) {
          int t = (rowb + r) & 4095;
          size_t addr = (size_t)which * QKVSZ +
                        ((size_t)(bb_ * NH + hh) * SEQ + t) * DH + dd;
          Cp[addr] = (bf16)acc[i][j][r];
        }
      }
    }
  }
}

// ---------------- agent pooling: agent[bh][p][d] = mean over 512 t of q ----------------
__global__ void agent_pool(const bf16* __restrict__ q, float* __restrict__ agent) {
  int bid = blockIdx.x;                  // 512 = bh*8 + p
  int p = bid & 7, bh = bid >> 3;
  int d = threadIdx.x & 63, c = threadIdx.x >> 6;   // c 0..3
  const bf16* base = q + ((size_t)bh * SEQ + p * 512) * DH + d;
  float s = 0.f;
  for (int i = c * 128; i < c * 128 + 128; ++i)
    s += (float)base[(size_t)i * DH];
  __shared__ float red[4][64];
  red[c][d] = s;
  __syncthreads();
  if (c == 0) {
    float v = (red[0][d] + red[1][d] + red[2][d] + red[3][d]) * (1.0f / 512.0f);
    agent[(size_t)(bh * POOL + p) * DH + d] = v;
  }
}

// ---- stage 1 fused: scores + chunk softmax + P@V partial, per (bh, t-chunk) ----
__global__ __launch_bounds__(256)
void stage1_fused(const bf16* __restrict__ k, const bf16* __restrict__ v,
                  const float* __restrict__ agent,
                  float* __restrict__ pm, float* __restrict__ pl,
                  float* __restrict__ pva) {
  const int tc = blockIdx.x, bh = blockIdx.y;
  const int tid = threadIdx.x;
  const int t0 = tc * TCL;

  __shared__ float agT[64][8];           // [d][p], pre-scaled
  __shared__ float se[TCL][9];           // exp(sc - m) per (t_local, p); +1 pad
  __shared__ float rm[4][8], rl[4][8];

  for (int i = tid; i < 512; i += 256) {
    int p = i >> 6, d = i & 63;
    agT[d][p] = agent[(size_t)bh * 512 + i] * SCALE_F;
  }
  __syncthreads();

  // phase 1: scores for t_local = tid, tid+256
  const bf16* kbase = k + ((size_t)bh * SEQ + t0) * DH;
  float sc[2][8] = {};
#pragma unroll
  for (int j = 0; j < 2; ++j) {
    const bf16* krow = kbase + (size_t)(j * 256 + tid) * DH;
#pragma unroll
    for (int dc = 0; dc < 8; ++dc) {
      bf16x8 k8 = *(const bf16x8*)(krow + dc * 8);
#pragma unroll
      for (int e = 0; e < 8; ++e) {
        float kv = (float)k8[e];
        int d = dc * 8 + e;
        float4 a0 = *(const float4*)&agT[d][0];
        float4 a1 = *(const float4*)&agT[d][4];
        sc[j][0] += a0.x * kv; sc[j][1] += a0.y * kv;
        sc[j][2] += a0.z * kv; sc[j][3] += a0.w * kv;
        sc[j][4] += a1.x * kv; sc[j][5] += a1.y * kv;
        sc[j][6] += a1.z * kv; sc[j][7] += a1.w * kv;
      }
    }
  }

  // block max per p
  float mx[8];
#pragma unroll
  for (int p = 0; p < 8; ++p) mx[p] = fmaxf(sc[0][p], sc[1][p]);
#pragma unroll
  for (int o = 32; o; o >>= 1)
#pragma unroll
    for (int p = 0; p < 8; ++p) mx[p] = fmaxf(mx[p], __shfl_xor(mx[p], o));
  if ((tid & 63) == 0)
#pragma unroll
    for (int p = 0; p < 8; ++p) rm[tid >> 6][p] = mx[p];
  __syncthreads();
  float m[8];
#pragma unroll
  for (int p = 0; p < 8; ++p)
    m[p] = fmaxf(fmaxf(rm[0][p], rm[1][p]), fmaxf(rm[2][p], rm[3][p]));

  // exp + block sum per p
  float sl[8] = {};
#pragma unroll
  for (int j = 0; j < 2; ++j) {
    int tl = j * 256 + tid;
#pragma unroll
    for (int p = 0; p < 8; ++p) {
      float e = __expf(sc[j][p] - m[p]);
      sl[p] += e;
      se[tl][p] = e;
    }
  }
#pragma unroll
  for (int o = 32; o; o >>= 1)
#pragma unroll
    for (int p = 0; p < 8; ++p) sl[p] += __shfl_xor(sl[p], o);
  if ((tid & 63) == 0)
#pragma unroll
    for (int p = 0; p < 8; ++p) rl[tid >> 6][p] = sl[p];
  __syncthreads();
  if (tid < 8) {
    float l = rl[0][tid] + rl[1][tid] + rl[2][tid] + rl[3][tid];
    pm[(size_t)(bh * TCH + tc) * 8 + tid] = m[tid];
    pl[(size_t)(bh * TCH + tc) * 8 + tid] = l;
  }

  // phase 2: pva[p][d] = sum_t se[t][p] * v[t][d]
  const int p  = tid >> 5;
  const int d0 = (tid & 31) * 2;
  const bf16* vbase = v + ((size_t)bh * SEQ + t0) * DH + d0;
  float a0 = 0.f, a1 = 0.f;
#pragma unroll 8
  for (int tl = 0; tl < TCL; ++tl) {
    float wgt = se[tl][p];
    bf16x2 v2 = *(const bf16x2*)(vbase + (size_t)tl * DH);
    a0 += wgt * (float)v2[0];
    a1 += wgt * (float)v2[1];
  }
  float* o = pva + ((size_t)(bh * TCH + tc) * 8 + p) * DH + d0;
  o[0] = a0; o[1] = a1;
}

// ---------------- combine chunk partials -> v_agent[bh][p][d] ----------------
__global__ void combine_vag(const float* __restrict__ pm, const float* __restrict__ pl,
                            const float* __restrict__ pva, float* __restrict__ vag) {
  int bh = blockIdx.x;
#pragma unroll
  for (int e = threadIdx.x; e < 512; e += 256) {
    int p = e >> 6, d = e & 63;
    float M = -1e30f;
#pragma unroll
    for (int tc = 0; tc < TCH; ++tc)
      M = fmaxf(M, pm[(size_t)(bh * TCH + tc) * 8 + p]);
    float L = 0.f, acc = 0.f;
#pragma unroll
    for (int tc = 0; tc < TCH; ++tc) {
      float w = __expf(pm[(size_t)(bh * TCH + tc) * 8 + p] - M);
      L   += w * pl[(size_t)(bh * TCH + tc) * 8 + p];
      acc += w * pva[((size_t)(bh * TCH + tc) * 8 + p) * DH + d];
    }
    vag[(size_t)bh * 512 + e] = acc / L;
  }
}

// ---------------- stage 2: out[t][h*64+d] via softmax(q.agent) @ v_agent ----------------
__global__ __launch_bounds__(256)
void stage2_out(const bf16* __restrict__ q, const float* __restrict__ agent,
                const float* __restrict__ vag, bf16* __restrict__ outa) {
  const int bh = blockIdx.y;
  const int t  = blockIdx.x * 256 + threadIdx.x;
  const int tid = threadIdx.x;

  __shared__ float agT[64][8], vaT[64][8];
  for (int i = tid; i < 512; i += 256) {
    int p = i >> 6, d = i & 63;
    agT[d][p] = agent[(size_t)bh * 512 + i] * SCALE_F;
    vaT[d][p] = vag[(size_t)bh * 512 + i];
  }
  __syncthreads();

  const bf16* qrow = q + ((size_t)bh * SEQ + t) * DH;
  float sc[8] = {};
#pragma unroll
  for (int dc = 0; dc < 8; ++dc) {
    bf16x8 q8 = *(const bf16x8*)(qrow + dc * 8);
#pragma unroll
    for (int e = 0; e < 8; ++e) {
      float qv = (float)q8[e];
      int d = dc * 8 + e;
      float4 a0 = *(const float4*)&agT[d][0];
      float4 a1 = *(const float4*)&agT[d][4];
      sc[0] += a0.x * qv; sc[1] += a0.y * qv; sc[2] += a0.z * qv; sc[3] += a0.w * qv;
      sc[4] += a1.x * qv; sc[5] += a1.y * qv; sc[6] += a1.z * qv; sc[7] += a1.w * qv;
    }
  }
  float m = sc[0];
#pragma unroll
  for (int p = 1; p < 8; ++p) m = fmaxf(m, sc[p]);
  float wsum = 0.f, wgt[8];
#pragma unroll
  for (int p = 0; p < 8; ++p) { wgt[p] = __expf(sc[p] - m); wsum += wgt[p]; }
  float inv = 1.0f / wsum;
#pragma unroll
  for (int p = 0; p < 8; ++p) wgt[p] *= inv;

  int b = bh >> 4, h = bh & 15;
  bf16* orow = outa + ((size_t)(b * SEQ + t)) * DIMV + h * DH;
#pragma unroll
  for (int dc = 0; dc < 8; ++dc) {
    bf16x8 o8;
#pragma unroll
    for (int e = 0; e < 8; ++e) {
      int d = dc * 8 + e;
      float4 v0 = *(const float4*)&vaT[d][0];
      float4 v1 = *(const float4*)&vaT[d][4];
      float vv = wgt[0] * v0.x + wgt[1] * v0.y + wgt[2] * v0.z + wgt[3] * v0.w
               + wgt[4] * v1.x + wgt[5] * v1.y + wgt[6] * v1.z + wgt[7] * v1.w;
      o8[e] = (bf16)vv;
    }
    *(bf16x8*)(orow + dc * 8) = o8;
  }
}

extern "C" void kernel_launch(void* const* d_in, const int* in_sizes, int n_in,
                              void* d_out, int out_size, void* d_ws, size_t ws_size,
                              hipStream_t stream) {
  const float* x    = (const float*)d_in[0];   // [4,4096,1024] fp32
  const float* Wqkv = (const float*)d_in[1];   // [1024,3072]   fp32
  const float* Wo   = (const float*)d_in[2];   // [1024,1024]   fp32
  const float* bo   = (const float*)d_in[3];   // [1024]        fp32
  float* out = (float*)d_out;                  // [4,4096,1024] fp32

  // workspace layout:
  //   WqkvT 6M | WoT 2M | qkv planes 96M (q,k,v each [bh][t][d])
  //   union{ xb 32M (dead after gemm1) / outa 32M }
  //   agent 128K | pm 16K | pl 16K | pva 1M | vag 128K
  char* ws = (char*)d_ws;
  bf16* WqkvT = (bf16*)ws;                                   ws += (size_t)QKV_N * DIMV * 2;
  bf16* WoT   = (bf16*)ws;                                   ws += (size_t)DIMV * DIMV * 2;
  bf16* qkv   = (bf16*)ws;                                   ws += 3 * QKVSZ * 2;
  char* wsu   = ws;                                          ws += (size_t)M_TOTAL * DIMV * 2;
  bf16*  xb    = (bf16*)wsu;
  bf16*  outa  = (bf16*)wsu;
  float* agent = (float*)ws;                                 ws += 512 * 64 * 4;
  float* pm    = (float*)ws;                                 ws += BH * TCH * 8 * 4;
  float* pl    = (float*)ws;                                 ws += BH * TCH * 8 * 4;
  float* pva   = (float*)ws;                                 ws += (size_t)BH * TCH * 8 * DH * 4;
  float* vag   = (float*)ws;                                 ws += 512 * 64 * 4;

  const bf16* qp = qkv;
  const bf16* kp = qkv + QKVSZ;
  const bf16* vp = qkv + 2 * QKVSZ;

  convert_x<<<(size_t)M_TOTAL * DIMV / (256 * 8), 256, 0, stream>>>(x, xb);
  transpose_f32_bf16<<<dim3(QKV_N / 32, DIMV / 32), 256, 0, stream>>>(Wqkv, WqkvT, DIMV, QKV_N);
  transpose_f32_bf16<<<dim3(DIMV / 32, DIMV / 32), 256, 0, stream>>>(Wo, WoT, DIMV, DIMV);

  // qkv = x @ Wqkv, scattered to split planes
  gemm_bt<0><<<dim3(QKV_N / 128, M_TOTAL / 128), 256, 0, stream>>>(
      xb, WqkvT, (void*)qkv, nullptr, M_TOTAL, QKV_N, DIMV);

  agent_pool<<<512, 256, 0, stream>>>(qp, agent);
  stage1_fused<<<dim3(TCH, BH), 256, 0, stream>>>(kp, vp, agent, pm, pl, pva);
  combine_vag<<<BH, 256, 0, stream>>>(pm, pl, pva, vag);
  stage2_out<<<dim3(SEQ / 256, BH), 256, 0, stream>>>(qp, agent, vag, outa);

  // out = outa @ Wo + bo (fp32 out)
  gemm_bt<1><<<dim3(DIMV / 128, M_TOTAL / 128), 256, 0, stream>>>(
      outa, WoT, (void*)out, bo, M_TOTAL, DIMV, DIMV);
}

// Round 4
// 363.486 us; speedup vs baseline: 1.1872x; 1.1586x over previous
//
#include <hip/hip_runtime.h>
#include <hip/hip_bf16.h>
#include <stdint.h>

typedef __bf16 bf16;
typedef __attribute__((ext_vector_type(8))) __bf16 bf16x8;
typedef __attribute__((ext_vector_type(2))) __bf16 bf16x2;
typedef __attribute__((ext_vector_type(4))) float f32x4;

#define NH 16
#define DH 64
#define POOL 8
#define BATCH 4
#define SEQ 4096
#define DIMV 1024
#define QKV_N (3*DIMV)
#define M_TOTAL (BATCH*SEQ)
#define SCALE_F 0.125f
#define BH (BATCH*NH)              // 64
#define QKVSZ ((size_t)BH*SEQ*DH)  // elems per q/k/v plane
#define TCH 8                      // t-split chunks for stage1
#define TCL (SEQ/TCH)              // 512 t per chunk
#define HP 128                     // h*p combined dim for P2/W2

#define AS1(p) ((const __attribute__((address_space(1))) void*)(p))
#define AS3(p) ((__attribute__((address_space(3))) void*)(p))

// ---------------- elementwise fp32 -> bf16 (8 elems/thread) ----------------
__global__ void convert_x(const float* __restrict__ in, bf16* __restrict__ out) {
  size_t i = ((size_t)blockIdx.x * 256 + threadIdx.x) * 8;
  float4 f0 = *(const float4*)(in + i);
  float4 f1 = *(const float4*)(in + i + 4);
  bf16x8 o;
  o[0] = (bf16)f0.x; o[1] = (bf16)f0.y; o[2] = (bf16)f0.z; o[3] = (bf16)f0.w;
  o[4] = (bf16)f1.x; o[5] = (bf16)f1.y; o[6] = (bf16)f1.z; o[7] = (bf16)f1.w;
  *(bf16x8*)(out + i) = o;
}

// ---------------- transpose fp32 [R][C] -> bf16 [C][R] ----------------
__global__ void transpose_f32_bf16(const float* __restrict__ in, bf16* __restrict__ out,
                                   int R, int C) {
  __shared__ float tile[32][33];
  int c0 = blockIdx.x * 32, r0 = blockIdx.y * 32;
  int tx = threadIdx.x & 31, ty = threadIdx.x >> 5;
  for (int i = ty; i < 32; i += 8)
    tile[i][tx] = in[(size_t)(r0 + i) * C + c0 + tx];
  __syncthreads();
  for (int i = ty; i < 32; i += 8)
    out[(size_t)(c0 + i) * R + r0 + tx] = (bf16)tile[tx][i];
}

// ---------------- MFMA GEMM: A[M][K] * B^T (B stored [N][K]) ----------------
// MODE 0: output bf16, scattered into split q/k/v planes [which][bh][t][d]
// MODE 2: output fp32 row-major + fp32 bias, B batched per 4096 rows of A
// LDS XOR swizzle: slot = kc ^ ((row>>1)&3) (verified: conflicts -> 0 in R3).
template <int MODE>
__global__ __launch_bounds__(256)
void gemm_bt(const bf16* __restrict__ A, const bf16* __restrict__ B,
             void* __restrict__ Cv, const float* __restrict__ bias,
             int M, int N, int K) {
  __shared__ bf16 As[128 * 32];
  __shared__ bf16 Bs[128 * 32];
  const int tid  = threadIdx.x;
  const int w    = tid >> 6;
  const int lane = tid & 63;
  const int m0 = blockIdx.y * 128, n0 = blockIdx.x * 128;
  const int wm = (w & 1) * 64, wn = (w >> 1) * 64;

  const bf16* Bb = (MODE == 2) ? (B + (size_t)(m0 >> 12) * N * K) : B;

  f32x4 acc[4][4] = {};

  const int g0  = w * 2;
  const int rig = lane >> 2;
  const int kcs = (lane & 3) ^ ((rig >> 1) & 3);
  const bf16* Ap0 = A + (size_t)(m0 + g0 * 16 + rig) * K + kcs * 8;
  const bf16* Ap1 = Ap0 + (size_t)16 * K;
  const bf16* Bp0 = Bb + (size_t)(n0 + g0 * 16 + rig) * K + kcs * 8;
  const bf16* Bp1 = Bp0 + (size_t)16 * K;
  bf16* AsW0 = As + g0 * 512;
  bf16* AsW1 = As + (g0 + 1) * 512;
  bf16* BsW0 = Bs + g0 * 512;
  bf16* BsW1 = Bs + (g0 + 1) * 512;

  for (int k0 = 0; k0 < K; k0 += 32) {
    __syncthreads();
    __builtin_amdgcn_global_load_lds(AS1(Ap0 + k0), AS3(AsW0), 16, 0, 0);
    __builtin_amdgcn_global_load_lds(AS1(Ap1 + k0), AS3(AsW1), 16, 0, 0);
    __builtin_amdgcn_global_load_lds(AS1(Bp0 + k0), AS3(BsW0), 16, 0, 0);
    __builtin_amdgcn_global_load_lds(AS1(Bp1 + k0), AS3(BsW1), 16, 0, 0);
    __syncthreads();

    bf16x8 a[4], b[4];
    const int C = lane >> 4;
#pragma unroll
    for (int i = 0; i < 4; ++i) {
      int ar = wm + i * 16 + (lane & 15);
      int sw = C ^ ((ar >> 1) & 3);
      a[i] = *(const bf16x8*)&As[ar * 32 + sw * 8];
    }
#pragma unroll
    for (int j = 0; j < 4; ++j) {
      int br = wn + j * 16 + (lane & 15);
      int sw = C ^ ((br >> 1) & 3);
      b[j] = *(const bf16x8*)&Bs[br * 32 + sw * 8];
    }
#pragma unroll
    for (int i = 0; i < 4; ++i)
#pragma unroll
      for (int j = 0; j < 4; ++j)
        acc[i][j] = __builtin_amdgcn_mfma_f32_16x16x32_bf16(a[i], b[j], acc[i][j], 0, 0, 0);
  }

  // epilogue: C/D layout col=lane&15, row=(lane>>4)*4+r
  const int cr = (lane >> 4) * 4;
  const int cc = lane & 15;
#pragma unroll
  for (int i = 0; i < 4; ++i) {
#pragma unroll
    for (int j = 0; j < 4; ++j) {
      int rowb = m0 + wm + i * 16 + cr;
      if (MODE == 2) {
        float* Cp = (float*)Cv;
        int col = n0 + wn + j * 16 + cc;
        float bb = bias[col];
#pragma unroll
        for (int r = 0; r < 4; ++r)
          Cp[(size_t)(rowb + r) * N + col] = acc[i][j][r] + bb;
      } else {
        bf16* Cp = (bf16*)Cv;
        int nbase = n0 + wn + j * 16;
        int which = nbase >> 10;
        int hh    = (nbase >> 6) & 15;
        int dd    = (nbase & 63) + cc;
        int bb_   = rowb >> 12;
#pragma unroll
        for (int r = 0; r < 4; ++r) {
          int t = (rowb + r) & 4095;
          size_t addr = (size_t)which * QKVSZ +
                        ((size_t)(bb_ * NH + hh) * SEQ + t) * DH + dd;
          Cp[addr] = (bf16)acc[i][j][r];
        }
      }
    }
  }
}

// ---------------- agent pooling: agent[bh][p][d] = mean over 512 t of q ----------------
__global__ void agent_pool(const bf16* __restrict__ q, float* __restrict__ agent) {
  int bid = blockIdx.x;                  // 512 = bh*8 + p
  int p = bid & 7, bh = bid >> 3;
  int d = threadIdx.x & 63, c = threadIdx.x >> 6;
  const bf16* base = q + ((size_t)bh * SEQ + p * 512) * DH + d;
  float s = 0.f;
  for (int i = c * 128; i < c * 128 + 128; ++i)
    s += (float)base[(size_t)i * DH];
  __shared__ float red[4][64];
  red[c][d] = s;
  __syncthreads();
  if (c == 0) {
    float v = (red[0][d] + red[1][d] + red[2][d] + red[3][d]) * (1.0f / 512.0f);
    agent[(size_t)(bh * POOL + p) * DH + d] = v;
  }
}

// ---- stage 1 fused: scores + chunk softmax + P@V partial, per (bh, t-chunk) ----
__global__ __launch_bounds__(256)
void stage1_fused(const bf16* __restrict__ k, const bf16* __restrict__ v,
                  const float* __restrict__ agent,
                  float* __restrict__ pm, float* __restrict__ pl,
                  float* __restrict__ pva) {
  const int tc = blockIdx.x, bh = blockIdx.y;
  const int tid = threadIdx.x;
  const int t0 = tc * TCL;

  __shared__ float agT[64][8];
  __shared__ float se[TCL][9];
  __shared__ float rm[4][8], rl[4][8];

  for (int i = tid; i < 512; i += 256) {
    int p = i >> 6, d = i & 63;
    agT[d][p] = agent[(size_t)bh * 512 + i] * SCALE_F;
  }
  __syncthreads();

  const bf16* kbase = k + ((size_t)bh * SEQ + t0) * DH;
  float sc[2][8] = {};
#pragma unroll
  for (int j = 0; j < 2; ++j) {
    const bf16* krow = kbase + (size_t)(j * 256 + tid) * DH;
#pragma unroll
    for (int dc = 0; dc < 8; ++dc) {
      bf16x8 k8 = *(const bf16x8*)(krow + dc * 8);
#pragma unroll
      for (int e = 0; e < 8; ++e) {
        float kv = (float)k8[e];
        int d = dc * 8 + e;
        float4 a0 = *(const float4*)&agT[d][0];
        float4 a1 = *(const float4*)&agT[d][4];
        sc[j][0] += a0.x * kv; sc[j][1] += a0.y * kv;
        sc[j][2] += a0.z * kv; sc[j][3] += a0.w * kv;
        sc[j][4] += a1.x * kv; sc[j][5] += a1.y * kv;
        sc[j][6] += a1.z * kv; sc[j][7] += a1.w * kv;
      }
    }
  }

  float mx[8];
#pragma unroll
  for (int p = 0; p < 8; ++p) mx[p] = fmaxf(sc[0][p], sc[1][p]);
#pragma unroll
  for (int o = 32; o; o >>= 1)
#pragma unroll
    for (int p = 0; p < 8; ++p) mx[p] = fmaxf(mx[p], __shfl_xor(mx[p], o));
  if ((tid & 63) == 0)
#pragma unroll
    for (int p = 0; p < 8; ++p) rm[tid >> 6][p] = mx[p];
  __syncthreads();
  float m[8];
#pragma unroll
  for (int p = 0; p < 8; ++p)
    m[p] = fmaxf(fmaxf(rm[0][p], rm[1][p]), fmaxf(rm[2][p], rm[3][p]));

  float sl[8] = {};
#pragma unroll
  for (int j = 0; j < 2; ++j) {
    int tl = j * 256 + tid;
#pragma unroll
    for (int p = 0; p < 8; ++p) {
      float e = __expf(sc[j][p] - m[p]);
      sl[p] += e;
      se[tl][p] = e;
    }
  }
#pragma unroll
  for (int o = 32; o; o >>= 1)
#pragma unroll
    for (int p = 0; p < 8; ++p) sl[p] += __shfl_xor(sl[p], o);
  if ((tid & 63) == 0)
#pragma unroll
    for (int p = 0; p < 8; ++p) rl[tid >> 6][p] = sl[p];
  __syncthreads();
  if (tid < 8) {
    float l = rl[0][tid] + rl[1][tid] + rl[2][tid] + rl[3][tid];
    pm[(size_t)(bh * TCH + tc) * 8 + tid] = m[tid];
    pl[(size_t)(bh * TCH + tc) * 8 + tid] = l;
  }

  const int p  = tid >> 5;
  const int d0 = (tid & 31) * 2;
  const bf16* vbase = v + ((size_t)bh * SEQ + t0) * DH + d0;
  float a0 = 0.f, a1 = 0.f;
#pragma unroll 8
  for (int tl = 0; tl < TCL; ++tl) {
    float wgt = se[tl][p];
    bf16x2 v2 = *(const bf16x2*)(vbase + (size_t)tl * DH);
    a0 += wgt * (float)v2[0];
    a1 += wgt * (float)v2[1];
  }
  float* o = pva + ((size_t)(bh * TCH + tc) * 8 + p) * DH + d0;
  o[0] = a0; o[1] = a1;
}

// ---------------- combine chunk partials -> v_agent[bh][p][d] ----------------
__global__ void combine_vag(const float* __restrict__ pm, const float* __restrict__ pl,
                            const float* __restrict__ pva, float* __restrict__ vag) {
  int bh = blockIdx.x;
#pragma unroll
  for (int e = threadIdx.x; e < 512; e += 256) {
    int p = e >> 6, d = e & 63;
    float M = -1e30f;
#pragma unroll
    for (int tc = 0; tc < TCH; ++tc)
      M = fmaxf(M, pm[(size_t)(bh * TCH + tc) * 8 + p]);
    float L = 0.f, acc = 0.f;
#pragma unroll
    for (int tc = 0; tc < TCH; ++tc) {
      float w = __expf(pm[(size_t)(bh * TCH + tc) * 8 + p] - M);
      L   += w * pl[(size_t)(bh * TCH + tc) * 8 + p];
      acc += w * pva[((size_t)(bh * TCH + tc) * 8 + p) * DH + d];
    }
    vag[(size_t)bh * 512 + e] = acc / L;
  }
}

// ---- W2T[b][n][hp] = sum_d vag[b][hp][d] * WoT[n][h*64+d]  (bf16 out) ----
// grid (64 n-chunks of 16, 4 b), 256 threads = 16 n x 16 h
__global__ void w2_build(const float* __restrict__ vag, const bf16* __restrict__ WoT,
                         bf16* __restrict__ W2T) {
  int b = blockIdx.y;
  int n = blockIdx.x * 16 + (threadIdx.x & 15);
  int h = threadIdx.x >> 4;
  __shared__ float vg[128][65];    // +1 pad: breaks row-stride bank aliasing
  for (int i = threadIdx.x; i < 128 * 64; i += 256)
    vg[i >> 6][i & 63] = vag[(size_t)b * 128 * 64 + i];
  __syncthreads();
  float acc[8] = {};
  const bf16* wrow = WoT + (size_t)n * DIMV + h * 64;
#pragma unroll
  for (int dv = 0; dv < 8; ++dv) {
    bf16x8 wv = *(const bf16x8*)(wrow + dv * 8);
#pragma unroll
    for (int e = 0; e < 8; ++e) {
      float wf = (float)wv[e];
      int d = dv * 8 + e;
#pragma unroll
      for (int p = 0; p < 8; ++p) acc[p] += vg[h * 8 + p][d] * wf;
    }
  }
  bf16x8 o;
#pragma unroll
  for (int p = 0; p < 8; ++p) o[p] = (bf16)acc[p];
  *(bf16x8*)&W2T[((size_t)b * DIMV + n) * HP + h * 8] = o;
}

// ---- P2[b*4096+t][h*8+p] = softmax_p(q . agent * SCALE)  (bf16) ----
__global__ __launch_bounds__(256)
void p2_build(const bf16* __restrict__ q, const float* __restrict__ agent,
              bf16* __restrict__ P2) {
  const int bh = blockIdx.y;
  const int t  = blockIdx.x * 256 + threadIdx.x;
  const int tid = threadIdx.x;

  __shared__ float agT[64][8];
  for (int i = tid; i < 512; i += 256) {
    int p = i >> 6, d = i & 63;
    agT[d][p] = agent[(size_t)bh * 512 + i] * SCALE_F;
  }
  __syncthreads();

  const bf16* qrow = q + ((size_t)bh * SEQ + t) * DH;
  float sc[8] = {};
#pragma unroll
  for (int dc = 0; dc < 8; ++dc) {
    bf16x8 q8 = *(const bf16x8*)(qrow + dc * 8);
#pragma unroll
    for (int e = 0; e < 8; ++e) {
      float qv = (float)q8[e];
      int d = dc * 8 + e;
      float4 a0 = *(const float4*)&agT[d][0];
      float4 a1 = *(const float4*)&agT[d][4];
      sc[0] += a0.x * qv; sc[1] += a0.y * qv; sc[2] += a0.z * qv; sc[3] += a0.w * qv;
      sc[4] += a1.x * qv; sc[5] += a1.y * qv; sc[6] += a1.z * qv; sc[7] += a1.w * qv;
    }
  }
  float m = sc[0];
#pragma unroll
  for (int p = 1; p < 8; ++p) m = fmaxf(m, sc[p]);
  float wsum = 0.f, wgt[8];
#pragma unroll
  for (int p = 0; p < 8; ++p) { wgt[p] = __expf(sc[p] - m); wsum += wgt[p]; }
  float inv = 1.0f / wsum;
  int b = bh >> 4, h = bh & 15;
  bf16x8 o8;
#pragma unroll
  for (int p = 0; p < 8; ++p) o8[p] = (bf16)(wgt[p] * inv);
  *(bf16x8*)&P2[((size_t)(b * SEQ + t)) * HP + h * 8] = o8;
}

extern "C" void kernel_launch(void* const* d_in, const int* in_sizes, int n_in,
                              void* d_out, int out_size, void* d_ws, size_t ws_size,
                              hipStream_t stream) {
  const float* x    = (const float*)d_in[0];   // [4,4096,1024] fp32
  const float* Wqkv = (const float*)d_in[1];   // [1024,3072]   fp32
  const float* Wo   = (const float*)d_in[2];   // [1024,1024]   fp32
  const float* bo   = (const float*)d_in[3];   // [1024]        fp32
  float* out = (float*)d_out;                  // [4,4096,1024] fp32

  // workspace:
  //   WqkvT 6M | WoT 2M | qkv 96M | union{ xb 32M / (P2 4M | W2T 1M) }
  //   agent 128K | pm 16K | pl 16K | pva 1M | vag 128K
  char* ws = (char*)d_ws;
  bf16* WqkvT = (bf16*)ws;                                   ws += (size_t)QKV_N * DIMV * 2;
  bf16* WoT   = (bf16*)ws;                                   ws += (size_t)DIMV * DIMV * 2;
  bf16* qkv   = (bf16*)ws;                                   ws += 3 * QKVSZ * 2;
  char* wsu   = ws;                                          ws += (size_t)M_TOTAL * DIMV * 2;
  bf16*  xb    = (bf16*)wsu;
  bf16*  P2    = (bf16*)wsu;                                  // 4 MB (after xb dead)
  bf16*  W2T   = (bf16*)(wsu + (size_t)M_TOTAL * HP * 2);     // 1 MB
  float* agent = (float*)ws;                                 ws += 512 * 64 * 4;
  float* pm    = (float*)ws;                                 ws += BH * TCH * 8 * 4;
  float* pl    = (float*)ws;                                 ws += BH * TCH * 8 * 4;
  float* pva   = (float*)ws;                                 ws += (size_t)BH * TCH * 8 * DH * 4;
  float* vag   = (float*)ws;                                 ws += 512 * 64 * 4;

  const bf16* qp = qkv;
  const bf16* kp = qkv + QKVSZ;
  const bf16* vp = qkv + 2 * QKVSZ;

  convert_x<<<(size_t)M_TOTAL * DIMV / (256 * 8), 256, 0, stream>>>(x, xb);
  transpose_f32_bf16<<<dim3(QKV_N / 32, DIMV / 32), 256, 0, stream>>>(Wqkv, WqkvT, DIMV, QKV_N);
  transpose_f32_bf16<<<dim3(DIMV / 32, DIMV / 32), 256, 0, stream>>>(Wo, WoT, DIMV, DIMV);

  // GEMM1: qkv = x @ Wqkv, scattered to split q/k/v planes
  gemm_bt<0><<<dim3(QKV_N / 128, M_TOTAL / 128), 256, 0, stream>>>(
      xb, WqkvT, (void*)qkv, nullptr, M_TOTAL, QKV_N, DIMV);

  agent_pool<<<512, 256, 0, stream>>>(qp, agent);
  p2_build<<<dim3(SEQ / 256, BH), 256, 0, stream>>>(qp, agent, P2);
  stage1_fused<<<dim3(TCH, BH), 256, 0, stream>>>(kp, vp, agent, pm, pl, pva);
  combine_vag<<<BH, 256, 0, stream>>>(pm, pl, pva, vag);
  w2_build<<<dim3(DIMV / 16, BATCH), 256, 0, stream>>>(vag, WoT, W2T);

  // out = P2 @ W2T(batched) + bo   (fp32 out, K=128)
  gemm_bt<2><<<dim3(DIMV / 128, M_TOTAL / 128), 256, 0, stream>>>(
      P2, W2T, (void*)out, bo, M_TOTAL, DIMV, HP);
}

// Round 5
// 353.837 us; speedup vs baseline: 1.2196x; 1.0273x over previous
//
#include <hip/hip_runtime.h>
#include <hip/hip_bf16.h>
#include <stdint.h>

typedef __bf16 bf16;
typedef __attribute__((ext_vector_type(8))) __bf16 bf16x8;
typedef __attribute__((ext_vector_type(2))) __bf16 bf16x2;
typedef __attribute__((ext_vector_type(4))) float f32x4;

#define NH 16
#define DH 64
#define POOL 8
#define BATCH 4
#define SEQ 4096
#define DIMV 1024
#define QKV_N (3*DIMV)
#define M_TOTAL (BATCH*SEQ)
#define SCALE_F 0.125f
// agent buffer holds SUMS over 512 t (from GEMM1-epilogue atomics);
// consumers fold mean (1/512) into the pre-softmax dot: exact.
#define AGS_F (SCALE_F / 512.0f)
#define BH (BATCH*NH)              // 64
#define QKVSZ ((size_t)BH*SEQ*DH)  // elems per q/k/v plane
#define TCH 16                     // t-split chunks for stage1
#define TCL (SEQ/TCH)              // 256 t per chunk
#define HP 128                     // h*p combined dim for P2/W2

#define AS1(p) ((const __attribute__((address_space(1))) void*)(p))
#define AS3(p) ((__attribute__((address_space(3))) void*)(p))

// ---------------- elementwise fp32 -> bf16 (8 elems/thread) ----------------
__global__ void convert_x(const float* __restrict__ in, bf16* __restrict__ out) {
  size_t i = ((size_t)blockIdx.x * 256 + threadIdx.x) * 8;
  float4 f0 = *(const float4*)(in + i);
  float4 f1 = *(const float4*)(in + i + 4);
  bf16x8 o;
  o[0] = (bf16)f0.x; o[1] = (bf16)f0.y; o[2] = (bf16)f0.z; o[3] = (bf16)f0.w;
  o[4] = (bf16)f1.x; o[5] = (bf16)f1.y; o[6] = (bf16)f1.z; o[7] = (bf16)f1.w;
  *(bf16x8*)(out + i) = o;
}

// ---------------- transpose fp32 [R][C] -> bf16 [C][R] ----------------
__global__ void transpose_f32_bf16(const float* __restrict__ in, bf16* __restrict__ out,
                                   int R, int C) {
  __shared__ float tile[32][33];
  int c0 = blockIdx.x * 32, r0 = blockIdx.y * 32;
  int tx = threadIdx.x & 31, ty = threadIdx.x >> 5;
  for (int i = ty; i < 32; i += 8)
    tile[i][tx] = in[(size_t)(r0 + i) * C + c0 + tx];
  __syncthreads();
  for (int i = ty; i < 32; i += 8)
    out[(size_t)(c0 + i) * R + r0 + tx] = (bf16)tile[tx][i];
}

// ---------------- MFMA GEMM: A[M][K] * B^T (B stored [N][K]) ----------------
// MODE 0: bf16 out scattered to split q/k/v planes; q-blocks also accumulate
//         agent pooling sums (fp32 atomics) in the epilogue.
// MODE 2: fp32 out row-major + fp32 bias, B batched per 4096 rows of A.
// LDS XOR swizzle: slot = kc ^ ((row>>1)&3) (verified: conflicts -> 0 in R3).
template <int MODE>
__global__ __launch_bounds__(256)
void gemm_bt(const bf16* __restrict__ A, const bf16* __restrict__ B,
             void* __restrict__ Cv, const float* __restrict__ bias,
             float* __restrict__ agentSum, int M, int N, int K) {
  __shared__ bf16 As[128 * 32];
  __shared__ bf16 Bs[128 * 32];
  const int tid  = threadIdx.x;
  const int w    = tid >> 6;
  const int lane = tid & 63;
  const int m0 = blockIdx.y * 128, n0 = blockIdx.x * 128;
  const int wm = (w & 1) * 64, wn = (w >> 1) * 64;

  const bf16* Bb = (MODE == 2) ? (B + (size_t)(m0 >> 12) * N * K) : B;

  f32x4 acc[4][4] = {};

  const int g0  = w * 2;
  const int rig = lane >> 2;
  const int kcs = (lane & 3) ^ ((rig >> 1) & 3);
  const bf16* Ap0 = A + (size_t)(m0 + g0 * 16 + rig) * K + kcs * 8;
  const bf16* Ap1 = Ap0 + (size_t)16 * K;
  const bf16* Bp0 = Bb + (size_t)(n0 + g0 * 16 + rig) * K + kcs * 8;
  const bf16* Bp1 = Bp0 + (size_t)16 * K;
  bf16* AsW0 = As + g0 * 512;
  bf16* AsW1 = As + (g0 + 1) * 512;
  bf16* BsW0 = Bs + g0 * 512;
  bf16* BsW1 = Bs + (g0 + 1) * 512;

  for (int k0 = 0; k0 < K; k0 += 32) {
    __syncthreads();
    __builtin_amdgcn_global_load_lds(AS1(Ap0 + k0), AS3(AsW0), 16, 0, 0);
    __builtin_amdgcn_global_load_lds(AS1(Ap1 + k0), AS3(AsW1), 16, 0, 0);
    __builtin_amdgcn_global_load_lds(AS1(Bp0 + k0), AS3(BsW0), 16, 0, 0);
    __builtin_amdgcn_global_load_lds(AS1(Bp1 + k0), AS3(BsW1), 16, 0, 0);
    __syncthreads();

    bf16x8 a[4], b[4];
    const int C = lane >> 4;
#pragma unroll
    for (int i = 0; i < 4; ++i) {
      int ar = wm + i * 16 + (lane & 15);
      int sw = C ^ ((ar >> 1) & 3);
      a[i] = *(const bf16x8*)&As[ar * 32 + sw * 8];
    }
#pragma unroll
    for (int j = 0; j < 4; ++j) {
      int br = wn + j * 16 + (lane & 15);
      int sw = C ^ ((br >> 1) & 3);
      b[j] = *(const bf16x8*)&Bs[br * 32 + sw * 8];
    }
#pragma unroll
    for (int i = 0; i < 4; ++i)
#pragma unroll
      for (int j = 0; j < 4; ++j)
        acc[i][j] = __builtin_amdgcn_mfma_f32_16x16x32_bf16(a[i], b[j], acc[i][j], 0, 0, 0);
  }

  // epilogue: C/D layout col=lane&15, row=(lane>>4)*4+r
  const int cr = (lane >> 4) * 4;
  const int cc = lane & 15;
#pragma unroll
  for (int i = 0; i < 4; ++i) {
#pragma unroll
    for (int j = 0; j < 4; ++j) {
      int rowb = m0 + wm + i * 16 + cr;
      if (MODE == 2) {
        float* Cp = (float*)Cv;
        int col = n0 + wn + j * 16 + cc;
        float bb = bias[col];
#pragma unroll
        for (int r = 0; r < 4; ++r)
          Cp[(size_t)(rowb + r) * N + col] = acc[i][j][r] + bb;
      } else {
        bf16* Cp = (bf16*)Cv;
        int nbase = n0 + wn + j * 16;
        int which = nbase >> 10;
        int hh    = (nbase >> 6) & 15;
        int dd    = (nbase & 63) + cc;
        int bb_   = rowb >> 12;
#pragma unroll
        for (int r = 0; r < 4; ++r) {
          int t = (rowb + r) & 4095;
          size_t addr = (size_t)which * QKVSZ +
                        ((size_t)(bb_ * NH + hh) * SEQ + t) * DH + dd;
          Cp[addr] = (bf16)acc[i][j][r];
        }
      }
    }
  }

  // fused agent pooling: q-plane blocks only. One 128-row tile = one (b,p)
  // bucket (512 t per bucket, 128 | 512, aligned). Sum fp32 acc over rows,
  // atomicAdd per column into agentSum[(b*16+h)*8+p][d].
  if (MODE == 0 && blockIdx.x < 8) {
    __shared__ float pool_red[4][16][4];   // [wave][cc][j]
    float s[4];
#pragma unroll
    for (int j = 0; j < 4; ++j) {
      float t = 0.f;
#pragma unroll
      for (int i = 0; i < 4; ++i)
        t += acc[i][j][0] + acc[i][j][1] + acc[i][j][2] + acc[i][j][3];
      t += __shfl_xor(t, 16);
      t += __shfl_xor(t, 32);
      s[j] = t;
    }
    if (lane < 16) {
#pragma unroll
      for (int j = 0; j < 4; ++j) pool_red[w][lane][j] = s[j];
    }
    __syncthreads();
    if (tid < 128) {
      int wnH = tid >> 6, j = (tid >> 4) & 3, c2 = tid & 15;
      float v = pool_red[wnH * 2][c2][j] + pool_red[wnH * 2 + 1][c2][j];
      int nb  = n0 + wnH * 64 + j * 16;
      int hh  = (nb >> 6) & 15;
      int dd  = (nb & 63) + c2;
      int bb_ = m0 >> 12;
      int pp  = (m0 & 4095) >> 9;
      atomicAdd(&agentSum[((size_t)(bb_ * NH + hh) * POOL + pp) * DH + dd], v);
    }
  }
}

// ---- stage 1 fused: scores + chunk softmax + P@V partial, per (bh, t-chunk) ----
// 1024 blocks (16 chunks x 64 bh); phase2 uses 16B v loads + 4-way t-split.
__global__ __launch_bounds__(256)
void stage1_fused(const bf16* __restrict__ k, const bf16* __restrict__ v,
                  const float* __restrict__ agentSum,
                  float* __restrict__ pm, float* __restrict__ pl,
                  float* __restrict__ pva) {
  const int tc = blockIdx.x, bh = blockIdx.y;
  const int tid = threadIdx.x;
  const int t0 = tc * TCL;

  __shared__ float agT[64][8];           // [d][p], scaled by SCALE/512
  __shared__ float se[TCL][9];           // exp(sc-m), pad to 9
  __shared__ float rm[4][8], rl[4][8];
  __shared__ float pr[4][8][64];         // [to][p][d] partial PV

  for (int i = tid; i < 512; i += 256) {
    int p = i >> 6, d = i & 63;
    agT[d][p] = agentSum[(size_t)bh * 512 + i] * AGS_F;
  }
  __syncthreads();

  // phase 1: one t-row per thread
  const bf16* krow = k + ((size_t)bh * SEQ + t0 + tid) * DH;
  float sc[8] = {};
#pragma unroll
  for (int dc = 0; dc < 8; ++dc) {
    bf16x8 k8 = *(const bf16x8*)(krow + dc * 8);
#pragma unroll
    for (int e = 0; e < 8; ++e) {
      float kv = (float)k8[e];
      int d = dc * 8 + e;
      float4 a0 = *(const float4*)&agT[d][0];
      float4 a1 = *(const float4*)&agT[d][4];
      sc[0] += a0.x * kv; sc[1] += a0.y * kv; sc[2] += a0.z * kv; sc[3] += a0.w * kv;
      sc[4] += a1.x * kv; sc[5] += a1.y * kv; sc[6] += a1.z * kv; sc[7] += a1.w * kv;
    }
  }

  float mx[8];
#pragma unroll
  for (int p = 0; p < 8; ++p) mx[p] = sc[p];
#pragma unroll
  for (int o = 32; o; o >>= 1)
#pragma unroll
    for (int p = 0; p < 8; ++p) mx[p] = fmaxf(mx[p], __shfl_xor(mx[p], o));
  if ((tid & 63) == 0)
#pragma unroll
    for (int p = 0; p < 8; ++p) rm[tid >> 6][p] = mx[p];
  __syncthreads();
  float m[8];
#pragma unroll
  for (int p = 0; p < 8; ++p)
    m[p] = fmaxf(fmaxf(rm[0][p], rm[1][p]), fmaxf(rm[2][p], rm[3][p]));

  float sl[8];
#pragma unroll
  for (int p = 0; p < 8; ++p) {
    float e = __expf(sc[p] - m[p]);
    se[tid][p] = e;
    sl[p] = e;
  }
#pragma unroll
  for (int o = 32; o; o >>= 1)
#pragma unroll
    for (int p = 0; p < 8; ++p) sl[p] += __shfl_xor(sl[p], o);
  if ((tid & 63) == 0)
#pragma unroll
    for (int p = 0; p < 8; ++p) rl[tid >> 6][p] = sl[p];
  __syncthreads();
  if (tid < 8) {
    float l = rl[0][tid] + rl[1][tid] + rl[2][tid] + rl[3][tid];
    pm[(size_t)(bh * TCH + tc) * 8 + tid] = m[tid];
    pl[(size_t)(bh * TCH + tc) * 8 + tid] = l;
  }

  // phase 2: pva[p][d] = sum_t se[t][p] * v[t][d], 16B loads, 4-way t-split
  const int p  = tid >> 5;
  const int dg = tid & 7;          // d-octet
  const int to = (tid >> 3) & 3;   // t-offset
  const bf16* vb = v + ((size_t)bh * SEQ + t0 + to) * DH + dg * 8;
  float a8[8] = {};
  for (int tl = to; tl < TCL; tl += 4) {
    float wgt = se[tl][p];
    bf16x8 v8 = *(const bf16x8*)(vb + (size_t)(tl - to) * DH);
#pragma unroll
    for (int e = 0; e < 8; ++e) a8[e] += wgt * (float)v8[e];
  }
#pragma unroll
  for (int e = 0; e < 8; ++e) pr[to][p][dg * 8 + e] = a8[e];
  __syncthreads();
  if (to == 0) {
    float* o = pva + ((size_t)(bh * TCH + tc) * 8 + p) * DH + dg * 8;
#pragma unroll
    for (int e = 0; e < 8; ++e)
      o[e] = pr[0][p][dg * 8 + e] + pr[1][p][dg * 8 + e] +
             pr[2][p][dg * 8 + e] + pr[3][p][dg * 8 + e];
  }
}

// ---------------- combine chunk partials -> v_agent[bh][p][d] ----------------
__global__ void combine_vag(const float* __restrict__ pm, const float* __restrict__ pl,
                            const float* __restrict__ pva, float* __restrict__ vag) {
  int bh = blockIdx.x;
#pragma unroll
  for (int e = threadIdx.x; e < 512; e += 256) {
    int p = e >> 6, d = e & 63;
    float M = -1e30f;
#pragma unroll
    for (int tc = 0; tc < TCH; ++tc)
      M = fmaxf(M, pm[(size_t)(bh * TCH + tc) * 8 + p]);
    float L = 0.f, acc = 0.f;
#pragma unroll
    for (int tc = 0; tc < TCH; ++tc) {
      float w = __expf(pm[(size_t)(bh * TCH + tc) * 8 + p] - M);
      L   += w * pl[(size_t)(bh * TCH + tc) * 8 + p];
      acc += w * pva[((size_t)(bh * TCH + tc) * 8 + p) * DH + d];
    }
    vag[(size_t)bh * 512 + e] = acc / L;
  }
}

// ---- W2T[b][n][hp] = sum_d vag[b][hp][d] * WoT[n][h*64+d]  (bf16 out) ----
__global__ void w2_build(const float* __restrict__ vag, const bf16* __restrict__ WoT,
                         bf16* __restrict__ W2T) {
  int b = blockIdx.y;
  int n = blockIdx.x * 16 + (threadIdx.x & 15);
  int h = threadIdx.x >> 4;
  __shared__ float vg[128][65];
  for (int i = threadIdx.x; i < 128 * 64; i += 256)
    vg[i >> 6][i & 63] = vag[(size_t)b * 128 * 64 + i];
  __syncthreads();
  float acc[8] = {};
  const bf16* wrow = WoT + (size_t)n * DIMV + h * 64;
#pragma unroll
  for (int dv = 0; dv < 8; ++dv) {
    bf16x8 wv = *(const bf16x8*)(wrow + dv * 8);
#pragma unroll
    for (int e = 0; e < 8; ++e) {
      float wf = (float)wv[e];
      int d = dv * 8 + e;
#pragma unroll
      for (int p = 0; p < 8; ++p) acc[p] += vg[h * 8 + p][d] * wf;
    }
  }
  bf16x8 o;
#pragma unroll
  for (int p = 0; p < 8; ++p) o[p] = (bf16)acc[p];
  *(bf16x8*)&W2T[((size_t)b * DIMV + n) * HP + h * 8] = o;
}

// ---- P2[b*4096+t][h*8+p] = softmax_p(q . agent * SCALE)  (bf16) ----
__global__ __launch_bounds__(256)
void p2_build(const bf16* __restrict__ q, const float* __restrict__ agentSum,
              bf16* __restrict__ P2) {
  const int bh = blockIdx.y;
  const int t  = blockIdx.x * 256 + threadIdx.x;
  const int tid = threadIdx.x;

  __shared__ float agT[64][8];
  for (int i = tid; i < 512; i += 256) {
    int p = i >> 6, d = i & 63;
    agT[d][p] = agentSum[(size_t)bh * 512 + i] * AGS_F;
  }
  __syncthreads();

  const bf16* qrow = q + ((size_t)bh * SEQ + t) * DH;
  float sc[8] = {};
#pragma unroll
  for (int dc = 0; dc < 8; ++dc) {
    bf16x8 q8 = *(const bf16x8*)(qrow + dc * 8);
#pragma unroll
    for (int e = 0; e < 8; ++e) {
      float qv = (float)q8[e];
      int d = dc * 8 + e;
      float4 a0 = *(const float4*)&agT[d][0];
      float4 a1 = *(const float4*)&agT[d][4];
      sc[0] += a0.x * qv; sc[1] += a0.y * qv; sc[2] += a0.z * qv; sc[3] += a0.w * qv;
      sc[4] += a1.x * qv; sc[5] += a1.y * qv; sc[6] += a1.z * qv; sc[7] += a1.w * qv;
    }
  }
  float m = sc[0];
#pragma unroll
  for (int p = 1; p < 8; ++p) m = fmaxf(m, sc[p]);
  float wsum = 0.f, wgt[8];
#pragma unroll
  for (int p = 0; p < 8; ++p) { wgt[p] = __expf(sc[p] - m); wsum += wgt[p]; }
  float inv = 1.0f / wsum;
  int b = bh >> 4, h = bh & 15;
  bf16x8 o8;
#pragma unroll
  for (int p = 0; p < 8; ++p) o8[p] = (bf16)(wgt[p] * inv);
  *(bf16x8*)&P2[((size_t)(b * SEQ + t)) * HP + h * 8] = o8;
}

extern "C" void kernel_launch(void* const* d_in, const int* in_sizes, int n_in,
                              void* d_out, int out_size, void* d_ws, size_t ws_size,
                              hipStream_t stream) {
  const float* x    = (const float*)d_in[0];   // [4,4096,1024] fp32
  const float* Wqkv = (const float*)d_in[1];   // [1024,3072]   fp32
  const float* Wo   = (const float*)d_in[2];   // [1024,1024]   fp32
  const float* bo   = (const float*)d_in[3];   // [1024]        fp32
  float* out = (float*)d_out;                  // [4,4096,1024] fp32

  char* ws = (char*)d_ws;
  bf16* WqkvT = (bf16*)ws;                                   ws += (size_t)QKV_N * DIMV * 2;
  bf16* WoT   = (bf16*)ws;                                   ws += (size_t)DIMV * DIMV * 2;
  bf16* qkv   = (bf16*)ws;                                   ws += 3 * QKVSZ * 2;
  char* wsu   = ws;                                          ws += (size_t)M_TOTAL * DIMV * 2;
  bf16*  xb    = (bf16*)wsu;
  bf16*  P2    = (bf16*)wsu;                                  // 4 MB (after xb dead)
  bf16*  W2T   = (bf16*)(wsu + (size_t)M_TOTAL * HP * 2);     // 1 MB
  float* agent = (float*)ws;                                 ws += 512 * 64 * 4;
  float* pm    = (float*)ws;                                 ws += BH * TCH * 8 * 4;
  float* pl    = (float*)ws;                                 ws += BH * TCH * 8 * 4;
  float* pva   = (float*)ws;                                 ws += (size_t)BH * TCH * 8 * DH * 4;
  float* vag   = (float*)ws;                                 ws += 512 * 64 * 4;

  const bf16* qp = qkv;
  const bf16* kp = qkv + QKVSZ;
  const bf16* vp = qkv + 2 * QKVSZ;

  // agent accumulated by GEMM1-epilogue atomics -> zero it first
  hipMemsetAsync(agent, 0, 512 * 64 * 4, stream);

  convert_x<<<(size_t)M_TOTAL * DIMV / (256 * 8), 256, 0, stream>>>(x, xb);
  transpose_f32_bf16<<<dim3(QKV_N / 32, DIMV / 32), 256, 0, stream>>>(Wqkv, WqkvT, DIMV, QKV_N);
  transpose_f32_bf16<<<dim3(DIMV / 32, DIMV / 32), 256, 0, stream>>>(Wo, WoT, DIMV, DIMV);

  // GEMM1: qkv = x @ Wqkv (split planes) + fused q pooling sums
  gemm_bt<0><<<dim3(QKV_N / 128, M_TOTAL / 128), 256, 0, stream>>>(
      xb, WqkvT, (void*)qkv, nullptr, agent, M_TOTAL, QKV_N, DIMV);

  p2_build<<<dim3(SEQ / 256, BH), 256, 0, stream>>>(qp, agent, P2);
  stage1_fused<<<dim3(TCH, BH), 256, 0, stream>>>(kp, vp, agent, pm, pl, pva);
  combine_vag<<<BH, 256, 0, stream>>>(pm, pl, pva, vag);
  w2_build<<<dim3(DIMV / 16, BATCH), 256, 0, stream>>>(vag, WoT, W2T);

  // out = P2 @ W2T(batched) + bo   (fp32 out, K=128)
  gemm_bt<2><<<dim3(DIMV / 128, M_TOTAL / 128), 256, 0, stream>>>(
      P2, W2T, (void*)out, bo, nullptr, M_TOTAL, DIMV, HP);
}